// Round 2
// baseline (579.942 us; speedup 1.0000x reference)
//
#include <hip/hip_runtime.h>
#include <hip/hip_cooperative_groups.h>
#include <math.h>

namespace cg = cooperative_groups;

#define Hdim 1024
#define Vdim 50257
#define Ldim 512
#define NBLK 256
#define NTHR 1024
#define NWAVE 16

__device__ __forceinline__ float waveReduceSum(float v) {
    #pragma unroll
    for (int off = 32; off > 0; off >>= 1) v += __shfl_down(v, off, 64);
    return v;
}
__device__ __forceinline__ float waveReduceMax(float v) {
    #pragma unroll
    for (int off = 32; off > 0; off >>= 1) v = fmaxf(v, __shfl_down(v, off, 64));
    return v;
}
__device__ __forceinline__ float dot4(float4 a, float4 b) {
    return a.x * b.x + a.y * b.y + a.z * b.z + a.w * b.w;
}

// One persistent cooperative kernel. 256 blocks x 1024 threads = 1 block/CU.
// Stages separated by grid.sync(); per-block-redundant softmax avoids one sync.
__global__ __launch_bounds__(NTHR, 4) void k_fused(
    const int* __restrict__ xp, const float* __restrict__ hidden,
    const float* __restrict__ enc, const float* __restrict__ emb,
    const float* __restrict__ Ww, const float* __restrict__ bw,
    const float* __restrict__ Wc, const float* __restrict__ bc,
    const float* __restrict__ Wih, const float* __restrict__ Whh,
    const float* __restrict__ bih, const float* __restrict__ bhh,
    const float* __restrict__ Wo, const float* __restrict__ bo,
    float* __restrict__ out_logp, float* __restrict__ out_h,
    float* __restrict__ out_w, float* __restrict__ ws)
{
    cg::grid_group grid = cg::this_grid();

    __shared__ float sweights[Ldim];
    __shared__ float red[NWAVE];
    __shared__ float red2[NWAVE];
    __shared__ float4 red4[8];
    __shared__ float slz;

    // workspace layout (floats)
    float* att  = ws;                 // 512
    float* gh   = ws + 512;           // 3072
    float* wctx = ws + 3584;          // 1024 (16B-aligned: 3584*4=14336)
    float* cvec = ws + 4608;          // 1024
    float* hnew = ws + 5632;          // 1024
    float* pm   = ws + 6656;          // 256
    float* ps   = ws + 6912;          // 256

    const int t = threadIdx.x, b = blockIdx.x;
    const int lane = t & 63, iw = t >> 6;
    const int tok = xp[0];
    const float4* embv = (const float4*)(emb + (size_t)tok * Hdim);
    const float4* hv   = (const float4*)hidden;

    // ---- S1: att[l] = Ww[l,:]·[emb;h]+bw (rows 0..511)
    //          gh[r]  = Whh[r,:]·h+bhh     (rows 512..3583)
    //          14 rows per block, one row per wave (256*14 = 3584 exactly)
    if (iw < 14) {
        const int r = b * 14 + iw;
        if (r < Ldim) {
            const float4* wrow = (const float4*)(Ww + (size_t)r * (2 * Hdim));
            float acc = 0.f;
            #pragma unroll
            for (int k = 0; k < 8; ++k) {
                const int j = lane + 64 * k;
                const float4 w = wrow[j];
                const float4 c = (j < 256) ? embv[j] : hv[j - 256];
                acc += dot4(w, c);
            }
            acc = waveReduceSum(acc);
            if (lane == 0) att[r] = acc + bw[r];
        } else {
            const int r2 = r - Ldim;
            const float4* wrow = (const float4*)(Whh + (size_t)r2 * Hdim);
            float acc = 0.f;
            #pragma unroll
            for (int k = 0; k < 4; ++k) {
                const int j = lane + 64 * k;
                acc += dot4(wrow[j], hv[j]);
            }
            acc = waveReduceSum(acc);
            if (lane == 0) gh[r2] = acc + bhh[r2];
        }
    }
    grid.sync();

    // ---- S2: softmax(att) computed redundantly in EVERY block (512 L2 reads)
    {
        const float v = (t < Ldim) ? att[t] : -1e30f;
        float wm = waveReduceMax(v);
        if (lane == 0) red[iw] = wm;
        __syncthreads();
        float m = red[0];
        #pragma unroll
        for (int i = 1; i < NWAVE; ++i) m = fmaxf(m, red[i]);
        const float e = (t < Ldim) ? __expf(v - m) : 0.f;
        float wsum = waveReduceSum(e);
        if (lane == 0) red2[iw] = wsum;
        __syncthreads();
        float s = red2[0];
        #pragma unroll
        for (int i = 1; i < NWAVE; ++i) s += red2[i];
        if (t < Ldim) {
            const float wgt = e / s;
            sweights[t] = wgt;            // same thread reads it in S3 — no sync needed
            if (b == 0) out_w[t] = wgt;   // output 3
        }
    }

    // ---- S3: wctx columns [4b, 4b+4): block b owns one float4 column group
    {
        float4 acc = make_float4(0.f, 0.f, 0.f, 0.f);
        if (t < Ldim) {
            const float wgt = sweights[t];
            const float4 e = *(const float4*)(enc + (size_t)t * Hdim + 4 * b);
            acc.x = wgt * e.x; acc.y = wgt * e.y; acc.z = wgt * e.z; acc.w = wgt * e.w;
        }
        acc.x = waveReduceSum(acc.x);
        acc.y = waveReduceSum(acc.y);
        acc.z = waveReduceSum(acc.z);
        acc.w = waveReduceSum(acc.w);
        __syncthreads();                   // guard red4 reuse across iterations of nothing; cheap
        if (lane == 0 && iw < 8) red4[iw] = acc;
        __syncthreads();
        if (t == 0) {
            float4 tot = red4[0];
            #pragma unroll
            for (int i = 1; i < 8; ++i) {
                tot.x += red4[i].x; tot.y += red4[i].y;
                tot.z += red4[i].z; tot.w += red4[i].w;
            }
            ((float4*)wctx)[b] = tot;
        }
    }
    grid.sync();

    // ---- S4: cvec[r] = relu(Wc[r,:]·[emb;wctx]+bc), 4 rows/block (waves 0..3)
    if (iw < 4) {
        const int r = b * 4 + iw;
        const float4* wrow  = (const float4*)(Wc + (size_t)r * (2 * Hdim));
        const float4* wctxv = (const float4*)wctx;
        float acc = 0.f;
        #pragma unroll
        for (int k = 0; k < 8; ++k) {
            const int j = lane + 64 * k;
            const float4 w = wrow[j];
            const float4 c = (j < 256) ? embv[j] : wctxv[j - 256];
            acc += dot4(w, c);
        }
        acc = waveReduceSum(acc);
        if (lane == 0) cvec[r] = fmaxf(acc + bc[r], 0.f);
    }
    grid.sync();

    // ---- S5: GRU: rows j, j+H, j+2H of Wih + gate math, 4 rows/block
    if (iw < 4) {
        const int j = b * 4 + iw;
        const float4* cv = (const float4*)cvec;
        const float4* a0 = (const float4*)(Wih + (size_t)j * Hdim);
        const float4* a1 = (const float4*)(Wih + (size_t)(j + Hdim) * Hdim);
        const float4* a2 = (const float4*)(Wih + (size_t)(j + 2 * Hdim) * Hdim);
        float s0 = 0.f, s1 = 0.f, s2 = 0.f;
        #pragma unroll
        for (int k = 0; k < 4; ++k) {
            const int jj = lane + 64 * k;
            const float4 c = cv[jj];
            s0 += dot4(a0[jj], c);
            s1 += dot4(a1[jj], c);
            s2 += dot4(a2[jj], c);
        }
        s0 = waveReduceSum(s0);
        s1 = waveReduceSum(s1);
        s2 = waveReduceSum(s2);
        if (lane == 0) {
            const float gir = s0 + bih[j];
            const float giz = s1 + bih[j + Hdim];
            const float gin = s2 + bih[j + 2 * Hdim];
            const float rr = 1.f / (1.f + __expf(-(gir + gh[j])));
            const float zz = 1.f / (1.f + __expf(-(giz + gh[j + Hdim])));
            const float nn = tanhf(gin + rr * gh[j + 2 * Hdim]);
            const float h = (1.f - zz) * nn + zz * hidden[j];
            hnew[j]  = h;
            out_h[j] = h;                  // output 2
        }
    }
    grid.sync();

    // ---- S6: logits + per-wave online logsumexp. Wave-per-row, grid-strided.
    {
        const float4* hv4 = (const float4*)hnew;
        float4 hreg[4];
        #pragma unroll
        for (int k = 0; k < 4; ++k) hreg[k] = hv4[lane + 64 * k];

        float m = -1e30f, s = 0.f;
        const int g = b * NWAVE + iw;               // 0..4095
        for (int r = g; r < Vdim; r += NBLK * NWAVE) {
            const float4* wrow = (const float4*)(Wo + (size_t)r * Hdim);
            float acc = 0.f;
            #pragma unroll
            for (int k = 0; k < 4; ++k) acc += dot4(wrow[lane + 64 * k], hreg[k]);
            acc = waveReduceSum(acc);
            if (lane == 0) {
                const float v = acc + bo[r];
                out_logp[r] = v;
                const float nm = fmaxf(m, v);
                s = s * __expf(m - nm) + __expf(v - nm);
                m = nm;
            }
        }
        if (lane == 0) { red[iw] = m; red2[iw] = s; }
        __syncthreads();
        if (t == 0) {
            float M = red[0], S = red2[0];
            #pragma unroll
            for (int i = 1; i < NWAVE; ++i) {
                const float nm = fmaxf(M, red[i]);
                S = S * __expf(M - nm) + red2[i] * __expf(red[i] - nm);
                M = nm;
            }
            pm[b] = M; ps[b] = S;
        }
    }
    grid.sync();

    // ---- S7: combine 256 partials (redundant per block), subtract logZ
    {
        float m = -1e30f, s = 0.f;
        if (t < NBLK) { m = pm[t]; s = ps[t]; }
        #pragma unroll
        for (int off = 32; off > 0; off >>= 1) {
            const float om = __shfl_down(m, off, 64);
            const float os = __shfl_down(s, off, 64);
            const float nm = fmaxf(m, om);
            s = s * __expf(m - nm) + os * __expf(om - nm);
            m = nm;
        }
        __syncthreads();                    // red/red2 reuse guard
        if (lane == 0 && iw < 4) { red[iw] = m; red2[iw] = s; }
        __syncthreads();
        if (t == 0) {
            float M = red[0], S = red2[0];
            #pragma unroll
            for (int i = 1; i < 4; ++i) {
                const float nm = fmaxf(M, red[i]);
                S = S * __expf(M - nm) + red2[i] * __expf(red[i] - nm);
                M = nm;
            }
            slz = M + logf(S);
        }
        __syncthreads();
        const float lz = slz;
        const int i = b * NTHR + t;
        if (i < Vdim) out_logp[i] -= lz;
    }
}

extern "C" void kernel_launch(void* const* d_in, const int* in_sizes, int n_in,
                              void* d_out, int out_size, void* d_ws, size_t ws_size,
                              hipStream_t stream)
{
    const int*   x      = (const int*)  d_in[0];
    const float* hidden = (const float*)d_in[1];
    const float* enc    = (const float*)d_in[2];
    const float* emb    = (const float*)d_in[3];
    const float* Ww     = (const float*)d_in[4];
    const float* bw     = (const float*)d_in[5];
    const float* Wc     = (const float*)d_in[6];
    const float* bc     = (const float*)d_in[7];
    const float* Wih    = (const float*)d_in[8];
    const float* Whh    = (const float*)d_in[9];
    const float* bih    = (const float*)d_in[10];
    const float* bhh    = (const float*)d_in[11];
    const float* Wo     = (const float*)d_in[12];
    const float* bo     = (const float*)d_in[13];

    float* out      = (float*)d_out;
    float* out_logp = out;                 // [V]
    float* out_h    = out + Vdim;          // [H]
    float* out_w    = out + Vdim + Hdim;   // [L]
    float* ws       = (float*)d_ws;

    void* args[] = {
        (void*)&x, (void*)&hidden, (void*)&enc, (void*)&emb,
        (void*)&Ww, (void*)&bw, (void*)&Wc, (void*)&bc,
        (void*)&Wih, (void*)&Whh, (void*)&bih, (void*)&bhh,
        (void*)&Wo, (void*)&bo,
        (void*)&out_logp, (void*)&out_h, (void*)&out_w, (void*)&ws
    };
    hipLaunchCooperativeKernel((const void*)k_fused, dim3(NBLK), dim3(NTHR),
                               args, 0, stream);
}

// Round 3
// 423.943 us; speedup vs baseline: 1.3680x; 1.3680x over previous
//
#include <hip/hip_runtime.h>
#include <math.h>

#define Hdim 1024
#define Vdim 50257
#define Ldim 512
#define NB_LOG ((Vdim + 3) / 4)   // 12565 blocks, 4 rows each

__device__ __forceinline__ float waveReduceSum(float v) {
    #pragma unroll
    for (int off = 32; off > 0; off >>= 1) v += __shfl_down(v, off, 64);
    return v;
}
__device__ __forceinline__ float waveReduceMax(float v) {
    #pragma unroll
    for (int off = 32; off > 0; off >>= 1) v = fmaxf(v, __shfl_down(v, off, 64));
    return v;
}
__device__ __forceinline__ float dot4(float4 a, float4 b) {
    return a.x * b.x + a.y * b.y + a.z * b.z + a.w * b.w;
}
template<int NW>
__device__ __forceinline__ float blockReduceSum(float v, float* red) {
    v = waveReduceSum(v);
    const int lane = threadIdx.x & 63, wid = threadIdx.x >> 6;
    if (lane == 0) red[wid] = v;
    __syncthreads();
    float s = red[0];
    #pragma unroll
    for (int i = 1; i < NW; i++) s += red[i];
    __syncthreads();
    return s;
}

// ---- K1: blocks 0..511:    att[l] = Ww[l,:]·[emb;h] + bw[l]
//          blocks 512..3583: gh[r]  = Whh[r,:]·h + bhh[r]
//          block 3584:       zero wctx accumulator
__global__ __launch_bounds__(256) void k_att_gh(
    const int* __restrict__ xp, const float* __restrict__ hidden,
    const float* __restrict__ emb, const float* __restrict__ Ww,
    const float* __restrict__ bw, const float* __restrict__ Whh,
    const float* __restrict__ bhh, float* __restrict__ att,
    float* __restrict__ gh, float* __restrict__ wctx)
{
    __shared__ float red[4];
    const int t = threadIdx.x, bid = blockIdx.x;
    if (bid == 3584) {
        ((float4*)wctx)[t] = make_float4(0.f, 0.f, 0.f, 0.f);
        return;
    }
    float acc = 0.f;
    if (bid < Ldim) {
        const int tok = xp[0];
        const float4* wrow = (const float4*)(Ww + (size_t)bid * (2 * Hdim));
        const float4* ev   = (const float4*)(emb + (size_t)tok * Hdim);
        const float4* hv   = (const float4*)hidden;
        const float4 w0 = wrow[t],        c0 = ev[t];
        const float4 w1 = wrow[t + 256],  c1 = hv[t];
        acc = dot4(w0, c0) + dot4(w1, c1);
        acc = blockReduceSum<4>(acc, red);
        if (t == 0) att[bid] = acc + bw[bid];
    } else {
        const int r = bid - Ldim;
        const float4* wrow = (const float4*)(Whh + (size_t)r * Hdim);
        acc = dot4(wrow[t], ((const float4*)hidden)[t]);
        acc = blockReduceSum<4>(acc, red);
        if (t == 0) gh[r] = acc + bhh[r];
    }
}

// ---- K2: 64 blocks; each redundantly computes softmax(att) (512 vals from L2),
//          then accumulates its 8 encoder rows into wctx via atomics.
//          Block 0 also writes weights output.
__global__ __launch_bounds__(256) void k_wctx(
    const float* __restrict__ att, const float* __restrict__ enc,
    float* __restrict__ wctx, float* __restrict__ out_w)
{
    __shared__ float red[4];
    __shared__ float sw[Ldim];
    __shared__ float bm, bs;
    const int t = threadIdx.x, lane = t & 63, iw = t >> 6;
    const float v0 = att[t], v1 = att[t + 256];
    float m = waveReduceMax(fmaxf(v0, v1));
    if (lane == 0) red[iw] = m;
    __syncthreads();
    if (t == 0) bm = fmaxf(fmaxf(red[0], red[1]), fmaxf(red[2], red[3]));
    __syncthreads();
    const float e0 = __expf(v0 - bm), e1 = __expf(v1 - bm);
    float s = waveReduceSum(e0 + e1);
    __syncthreads();
    if (lane == 0) red[iw] = s;
    __syncthreads();
    if (t == 0) bs = red[0] + red[1] + red[2] + red[3];
    __syncthreads();
    const float w0 = e0 / bs, w1 = e1 / bs;
    sw[t] = w0; sw[t + 256] = w1;
    if (blockIdx.x == 0) { out_w[t] = w0; out_w[t + 256] = w1; }
    __syncthreads();

    float4 acc = make_float4(0.f, 0.f, 0.f, 0.f);
    #pragma unroll
    for (int i = 0; i < 8; ++i) {
        const int l = blockIdx.x * 8 + i;
        const float w = sw[l];
        const float4 e = ((const float4*)(enc + (size_t)l * Hdim))[t];
        acc.x += w * e.x; acc.y += w * e.y; acc.z += w * e.z; acc.w += w * e.w;
    }
    atomicAdd(&wctx[t * 4 + 0], acc.x);
    atomicAdd(&wctx[t * 4 + 1], acc.y);
    atomicAdd(&wctx[t * 4 + 2], acc.z);
    atomicAdd(&wctx[t * 4 + 3], acc.w);
}

// ---- K3: cvec[r] = relu(Wc[r,:]·[emb;wctx] + bc[r]) (1024 blocks)
__global__ __launch_bounds__(256) void k_wc(
    const int* __restrict__ xp, const float* __restrict__ emb,
    const float* __restrict__ wctx, const float* __restrict__ Wc,
    const float* __restrict__ bc, float* __restrict__ cvec)
{
    __shared__ float red[4];
    const int t = threadIdx.x, r = blockIdx.x;
    const int tok = xp[0];
    const float4* wrow = (const float4*)(Wc + (size_t)r * (2 * Hdim));
    const float4* ev   = (const float4*)(emb + (size_t)tok * Hdim);
    const float4* cv   = (const float4*)wctx;
    float acc = dot4(wrow[t], ev[t]) + dot4(wrow[t + 256], cv[t]);
    acc = blockReduceSum<4>(acc, red);
    if (t == 0) cvec[r] = fmaxf(acc + bc[r], 0.f);
}

// ---- K4: GRU rows j, j+H, j+2H + gate math → h_new[j] (1024 blocks)
__global__ __launch_bounds__(256) void k_gru(
    const float* __restrict__ Wih, const float* __restrict__ bih,
    const float* __restrict__ gh, const float* __restrict__ cvec,
    const float* __restrict__ hidden, float* __restrict__ hnew,
    float* __restrict__ out_h)
{
    __shared__ float red[4];
    const int t = threadIdx.x, j = blockIdx.x;
    const float4 c = ((const float4*)cvec)[t];
    const float4 a = ((const float4*)(Wih + (size_t)j * Hdim))[t];
    const float4 b = ((const float4*)(Wih + (size_t)(j + Hdim) * Hdim))[t];
    const float4 d = ((const float4*)(Wih + (size_t)(j + 2 * Hdim) * Hdim))[t];
    float s0 = dot4(a, c), s1 = dot4(b, c), s2 = dot4(d, c);
    s0 = blockReduceSum<4>(s0, red);
    s1 = blockReduceSum<4>(s1, red);
    s2 = blockReduceSum<4>(s2, red);
    if (t == 0) {
        const float gir = s0 + bih[j];
        const float giz = s1 + bih[j + Hdim];
        const float gin = s2 + bih[j + 2 * Hdim];
        const float rr = 1.f / (1.f + __expf(-(gir + gh[j])));
        const float zz = 1.f / (1.f + __expf(-(giz + gh[j + Hdim])));
        const float nn = tanhf(gin + rr * gh[j + 2 * Hdim]);
        const float h = (1.f - zz) * nn + zz * hidden[j];
        hnew[j]  = h;
        out_h[j] = h;
    }
}

// ---- K5: logits, 4 rows/block (one per wave) + fused bias + per-block
//          logsumexp partial (m, s) → pm/ps[block]
__global__ __launch_bounds__(256) void k_logits(
    const float* __restrict__ Wo, const float* __restrict__ bo,
    const float* __restrict__ h, float* __restrict__ logits,
    float* __restrict__ pm, float* __restrict__ ps)
{
    __shared__ float redv[4];
    const int t = threadIdx.x, lane = t & 63, iw = t >> 6;
    const int r = blockIdx.x * 4 + iw;
    float v = -INFINITY;
    if (r < Vdim) {
        const float4* wrow = (const float4*)(Wo + (size_t)r * Hdim);
        const float4* hv   = (const float4*)h;
        float acc = 0.f;
        #pragma unroll
        for (int k = 0; k < 4; ++k)
            acc += dot4(wrow[lane + 64 * k], hv[lane + 64 * k]);
        acc = waveReduceSum(acc);
        if (lane == 0) {
            v = acc + bo[r];
            logits[r] = v;
        }
    }
    if (lane == 0) redv[iw] = v;
    __syncthreads();
    if (t == 0) {
        float m = fmaxf(fmaxf(redv[0], redv[1]), fmaxf(redv[2], redv[3]));
        float s = 0.f;
        #pragma unroll
        for (int i = 0; i < 4; ++i) s += __expf(redv[i] - m);  // exp(-inf-m)=0
        pm[blockIdx.x] = m; ps[blockIdx.x] = s;
    }
}

// ---- K6: combine NB_LOG partials → logZ (1 block, 1024 threads)
__global__ __launch_bounds__(1024) void k_lse_final(
    const float* __restrict__ pm, const float* __restrict__ ps,
    float* __restrict__ logZ)
{
    __shared__ float redm[16], reds[16];
    const int t = threadIdx.x, lane = t & 63, iw = t >> 6;
    float m = -INFINITY, s = 0.f;
    for (int i = t; i < NB_LOG; i += 1024) {
        const float om = pm[i], os = ps[i];
        const float nm = fmaxf(m, om);
        s = s * __expf(m - nm) + os * __expf(om - nm);
        m = nm;
    }
    #pragma unroll
    for (int off = 32; off > 0; off >>= 1) {
        const float om = __shfl_down(m, off, 64);
        const float os = __shfl_down(s, off, 64);
        const float nm = fmaxf(m, om);
        s = s * __expf(m - nm) + os * __expf(om - nm);
        m = nm;
    }
    if (lane == 0) { redm[iw] = m; reds[iw] = s; }
    __syncthreads();
    if (t == 0) {
        float M = redm[0], S = reds[0];
        #pragma unroll
        for (int i = 1; i < 16; ++i) {
            const float nm = fmaxf(M, redm[i]);
            S = S * __expf(M - nm) + reds[i] * __expf(redm[i] - nm);
            M = nm;
        }
        logZ[0] = M + logf(S);
    }
}

// ---- K7: out[i] -= logZ
__global__ __launch_bounds__(256) void k_out(
    float* __restrict__ out, const float* __restrict__ logZ)
{
    const int i = blockIdx.x * 256 + threadIdx.x;
    if (i < Vdim) out[i] = out[i] - logZ[0];
}

extern "C" void kernel_launch(void* const* d_in, const int* in_sizes, int n_in,
                              void* d_out, int out_size, void* d_ws, size_t ws_size,
                              hipStream_t stream)
{
    const int*   x      = (const int*)  d_in[0];
    const float* hidden = (const float*)d_in[1];
    const float* enc    = (const float*)d_in[2];
    const float* emb    = (const float*)d_in[3];
    const float* Ww     = (const float*)d_in[4];
    const float* bw     = (const float*)d_in[5];
    const float* Wc     = (const float*)d_in[6];
    const float* bc     = (const float*)d_in[7];
    const float* Wih    = (const float*)d_in[8];
    const float* Whh    = (const float*)d_in[9];
    const float* bih    = (const float*)d_in[10];
    const float* bhh    = (const float*)d_in[11];
    const float* Wo     = (const float*)d_in[12];
    const float* bo     = (const float*)d_in[13];

    float* out      = (float*)d_out;
    float* out_logp = out;                 // [V]
    float* out_h    = out + Vdim;          // [H]
    float* out_w    = out + Vdim + Hdim;   // [L]

    float* ws   = (float*)d_ws;
    float* att  = ws;                      // 512
    float* gh   = ws + 512;                // 3072
    float* wctx = ws + 3584;               // 1024 (16B aligned)
    float* cvec = ws + 4608;               // 1024
    float* hnew = ws + 5632;               // 1024
    float* pm   = ws + 6656;               // NB_LOG
    float* psum = ws + 6656 + NB_LOG;      // NB_LOG
    float* logZ = ws + 6656 + 2 * NB_LOG;  // 1

    k_att_gh   <<<dim3(3585),             dim3(256),  0, stream>>>(x, hidden, emb, Ww, bw, Whh, bhh, att, gh, wctx);
    k_wctx     <<<dim3(64),               dim3(256),  0, stream>>>(att, enc, wctx, out_w);
    k_wc       <<<dim3(Hdim),             dim3(256),  0, stream>>>(x, emb, wctx, Wc, bc, cvec);
    k_gru      <<<dim3(Hdim),             dim3(256),  0, stream>>>(Wih, bih, gh, cvec, hidden, hnew, out_h);
    k_logits   <<<dim3(NB_LOG),           dim3(256),  0, stream>>>(Wo, bo, hnew, out_logp, pm, psum);
    k_lse_final<<<dim3(1),                dim3(1024), 0, stream>>>(pm, psum, logZ);
    k_out      <<<dim3((Vdim + 255) / 256), dim3(256), 0, stream>>>(out_logp, logZ);
}